// Round 5
// baseline (274.089 us; speedup 1.0000x reference)
//
#include <hip/hip_runtime.h>
#include <math.h>
#include <stdint.h>

#define BB 8
#define NCC 6
#define NBOX 900
#define NBOXES (NCC * NBOX)      // 5400 boxes per batch
#define NBC (BB * NCC)           // 48 cameras
#define ND 48
#define TPB_BOX 6                // threads per box in mask kernel (8 depths each)
#define NQ 400
#define REFSZ (BB * NQ * 3)
#define NPAD 5408
#define NBIN 1024
#define SELCAP 640               // survivor capacity (<400 + boundary-bin pop)

// nan_to_num applied to an f32-rounded double (matches ref's _nan_to_num on the f32 inverse)
__device__ __forceinline__ float nnf(double x) {
    float v = (float)x;
    if (isnan(v)) return 0.0f;
    if (isinf(v)) return v > 0.0f ? 1e6f : -1e6f;
    return v;
}

__device__ void invert3x3(const float* __restrict__ Kp, float* __restrict__ Ki) {
    double a00 = Kp[0], a01 = Kp[1], a02 = Kp[2];
    double a10 = Kp[4], a11 = Kp[5], a12 = Kp[6];
    double a20 = Kp[8], a21 = Kp[9], a22 = Kp[10];
    double c00 = a11 * a22 - a12 * a21;
    double c10 = a12 * a20 - a10 * a22;
    double c20 = a10 * a21 - a11 * a20;
    double det = a00 * c00 + a01 * c10 + a02 * c20;
    double id  = 1.0 / det;
    Ki[0] = nnf(c00 * id); Ki[1] = nnf((a02 * a21 - a01 * a22) * id); Ki[2] = nnf((a01 * a12 - a02 * a11) * id);
    Ki[3] = nnf(c10 * id); Ki[4] = nnf((a00 * a22 - a02 * a20) * id); Ki[5] = nnf((a02 * a10 - a00 * a12) * id);
    Ki[6] = nnf(c20 * id); Ki[7] = nnf((a01 * a20 - a00 * a21) * id); Ki[8] = nnf((a00 * a11 - a01 * a10) * id);
}

__device__ void invert4x4(const float* __restrict__ Ep, float* __restrict__ Ei) {
    double m[4][8];
    for (int i = 0; i < 4; ++i)
        for (int j = 0; j < 4; ++j) {
            m[i][j]     = (double)Ep[i * 4 + j];
            m[i][4 + j] = (i == j) ? 1.0 : 0.0;
        }
    for (int col = 0; col < 4; ++col) {
        int piv = col; double best = fabs(m[col][col]);
        for (int r = col + 1; r < 4; ++r) {
            double v = fabs(m[r][col]);
            if (v > best) { best = v; piv = r; }
        }
        if (piv != col)
            for (int j = 0; j < 8; ++j) { double tmp = m[col][j]; m[col][j] = m[piv][j]; m[piv][j] = tmp; }
        double ipv = 1.0 / m[col][col];
        for (int j = 0; j < 8; ++j) m[col][j] *= ipv;
        for (int r = 0; r < 4; ++r) {
            if (r == col) continue;
            double f = m[r][col];
            if (f != 0.0)
                for (int j = 0; j < 8; ++j) m[r][j] -= f * m[col][j];
        }
    }
    for (int i = 0; i < 16; ++i) Ei[i] = nnf(m[i / 4][4 + (i & 3)]);
}

// ---------------- kernel 1: per-(box, j) mask over 8 depths + area histogram ----------------
__global__ __launch_bounds__(256) void mask_kernel(const float* __restrict__ boxes,
                                                   const float* __restrict__ K,
                                                   const float* __restrict__ E,
                                                   uint8_t* __restrict__ mask_bytes,
                                                   uint32_t* __restrict__ area_bits,
                                                   int* __restrict__ hist) {
    __shared__ float sKi[2][9];
    __shared__ float sEv[2][16];

    int gbase = blockIdx.x * 256;
    int bc_lo = gbase / (NBOX * TPB_BOX);
    int bc_hi = (gbase + 255) / (NBOX * TPB_BOX);
    if (bc_hi > NBC - 1) bc_hi = NBC - 1;
    if (threadIdx.x == 0) {
        invert3x3(K + bc_lo * 16, sKi[0]);
        invert4x4(E + bc_lo * 16, sEv[0]);
    }
    if (threadIdx.x == 1 && bc_hi != bc_lo) {
        invert3x3(K + bc_hi * 16, sKi[1]);
        invert4x4(E + bc_hi * 16, sEv[1]);
    }
    __syncthreads();

    int gtid = gbase + threadIdx.x;
    if (gtid >= BB * NBOXES * TPB_BOX) return;
    int box = gtid / TPB_BOX;            // global box index = b*NBOXES + cn
    int j   = gtid - box * TPB_BOX;
    int bc  = box / NBOX;
    int b   = box / NBOXES;

    const float* bx = boxes + box * 4;
    float x1 = bx[0], y1 = bx[1], x2 = bx[2], y2 = bx[3];
    float area  = (x2 - x1) * (y2 - y1);
    bool  valid = (area > 5.0f) && (area < 197120.0f);
    uint32_t abv = __float_as_uint(area);
    if (j == 0) {
        area_bits[box] = abv;
        *(uint16_t*)(mask_bytes + box * 8 + 6) = 0;
    }

    uint32_t m8 = 0;
    if (valid) {
        int sel = (bc == bc_lo) ? 0 : 1;
        float Ki[9], Ev[16], Ep[12], Kp[11];
        #pragma unroll
        for (int i = 0; i < 9; ++i)  Ki[i] = sKi[sel][i];
        #pragma unroll
        for (int i = 0; i < 16; ++i) Ev[i] = sEv[sel][i];
        const float* Epp = E + bc * 16;
        #pragma unroll
        for (int i = 0; i < 12; ++i) Ep[i] = Epp[i];
        const float* Kpp = K + bc * 16;
        #pragma unroll
        for (int i = 0; i < 11; ++i) Kp[i] = Kpp[i];

        float cx = (x1 + x2) * 0.5f, cy = (y1 + y2) * 0.5f;
        const float step = (60.0f - 1.0f) / 47.0f;

        #pragma unroll
        for (int dd = 0; dd < 8; ++dd) {
            int d = j * 8 + dd;
            float z = (d == ND - 1) ? 60.0f : 1.0f + (float)d * step;
            float u0 = cx * z, u1 = cy * z;
            float pcx = Ki[0] * u0 + Ki[1] * u1 + Ki[2] * z;
            float pcy = Ki[3] * u0 + Ki[4] * u1 + Ki[5] * z;
            float pcz = Ki[6] * u0 + Ki[7] * u1 + Ki[8] * z;

            float X = Ep[0] * pcx + Ep[1] * pcy + Ep[2]  * pcz + Ep[3];
            float Y = Ep[4] * pcx + Ep[5] * pcy + Ep[6]  * pcz + Ep[7];
            float Z = Ep[8] * pcx + Ep[9] * pcy + Ep[10] * pcz + Ep[11];

            float q0 = Ev[0]  * X + Ev[1]  * Y + Ev[2]  * Z + Ev[3];
            float q1 = Ev[4]  * X + Ev[5]  * Y + Ev[6]  * Z + Ev[7];
            float q2 = Ev[8]  * X + Ev[9]  * Y + Ev[10] * Z + Ev[11];
            float q3 = Ev[12] * X + Ev[13] * Y + Ev[14] * Z + Ev[15];
            float w  = q3 + 1e-6f;
            float r0 = q0 / w, r1 = q1 / w, r2 = q2 / w;

            float p0 = Kp[0] * r0 + Kp[1] * r1 + Kp[2]  * r2;
            float p1 = Kp[4] * r0 + Kp[5] * r1 + Kp[6]  * r2;
            float p2 = Kp[8] * r0 + Kp[9] * r1 + Kp[10] * r2;
            float iz = p2 + 1e-6f;
            float ix = p0 / iz, iy = p1 / iz;

            float bs = 40.0f * (10.0f / (r2 + 1e-6f));
            bs = fminf(fmaxf(bs, 8.0f), 200.0f);
            float hh = bs / 2.0f;
            float px1 = ix - hh, py1 = iy - hh, px2 = ix + hh, py2 = iy + hh;

            float ix1 = fmaxf(px1, x1), iy1 = fmaxf(py1, y1);
            float ix2 = fminf(px2, x2), iy2 = fminf(py2, y2);
            float inter = fmaxf(ix2 - ix1, 0.0f) * fmaxf(iy2 - iy1, 0.0f);
            float a1 = (px2 - px1) * (py2 - py1);
            float iou = inter / (a1 + area - inter + 1e-6f);

            if (iou > 0.05f) m8 |= (1u << dd);
        }
    }
    mask_bytes[box * 8 + j] = (uint8_t)m8;
    if (m8) {
        int bin = (int)(abv >> 21) & (NBIN - 1);   // monotone in area (positive f32)
        atomicAdd(&hist[b * NBIN + bin], __popc(m8));
    }
}

// ---------------- kernel 2: per-batch top-400 select + output ----------------
// Area regime (total > 400): suffix-scan the 1024-bin weighted histogram to find
// B* = max bin with suffix-weight >= 400 (all top-400 keys have bin >= B*),
// one-sweep compact of survivor boxes, per-thread exact weighted rank over the
// <=SELCAP distinct keys, scatter (box,depth) into a 400-slot table, emit.
// Order regime (total <= 400): blocked prefix of per-box counts, scatter, emit.
__global__ __launch_bounds__(512) void select_kernel(const uint64_t* __restrict__ mask64,
                                                     const uint32_t* __restrict__ area_bits,
                                                     const float* __restrict__ boxes,
                                                     const float* __restrict__ K,
                                                     const float* __restrict__ E,
                                                     const int* __restrict__ hist,
                                                     float* __restrict__ out) {
    int b   = blockIdx.x;
    int tid = threadIdx.x;
    int lane = tid & 63, wv = tid >> 6;
    const uint64_t* mb = mask64 + b * NBOXES;
    const uint32_t* ab = area_bits + b * NBOXES;
    const int* hb = hist + b * NBIN;

    __shared__ uint64_t s_sel[SELCAP];
    __shared__ int      s_out[NQ];        // packed (cn<<6)|d, -1 = pad
    __shared__ int      s_scan[512];
    __shared__ int      s_wsum[8];
    __shared__ float    s_Ki[NCC][9];
    __shared__ int      s_B, s_cnt;

    if (tid < NCC) invert3x3(K + (b * NCC + tid) * 16, s_Ki[tid]);
    if (tid < NQ) s_out[tid] = -1;
    if (tid == 0) { s_B = 0; s_cnt = 0; }

    // ---- suffix scan of the 1024-bin weighted histogram (2 bins/thread) ----
    int h0 = hb[2 * tid];
    int h1 = hb[2 * tid + 1];
    int w  = h0 + h1;
    // within-wave inclusive suffix over lanes
    int suf = w;
    #pragma unroll
    for (int off = 1; off < 64; off <<= 1) {
        int v = __shfl_down(suf, off);
        if (lane + off < 64) suf += v;
    }
    if (lane == 0) s_wsum[wv] = suf;      // wave total
    __syncthreads();
    int above_waves = 0, total = 0;
    #pragma unroll
    for (int ww = 0; ww < 8; ++ww) {
        int v = s_wsum[ww];
        total += v;
        if (ww > wv) above_waves += v;
    }
    int S_incl = suf + above_waves;        // weight of bins >= 2*tid
    int above  = S_incl - w;               // weight of bins >  2*tid+1
    // boundary bin B*: unique crossing of NQ
    if (total > NQ) {
        int s1 = above + h1;               // suffix(2t+1)
        if (s1 >= NQ && above < NQ)      s_B = 2 * tid + 1;
        else if (S_incl >= NQ && s1 < NQ) s_B = 2 * tid;
    }
    __syncthreads();

    if (total > NQ) {
        // ======== AREA REGIME ========
        int Bstar = s_B;
        // one-sweep compact of survivors (bin >= B*)
        for (int t = tid; t < NBOXES; t += 512) {
            uint64_t mk = mb[t];
            if (!mk) continue;
            uint32_t abv = ab[t];
            int bin = (int)(abv >> 21) & (NBIN - 1);
            if (bin >= Bstar) {
                int p = atomicAdd(&s_cnt, 1);
                if (p < SELCAP)
                    s_sel[p] = ((uint64_t)abv << 32) |
                               ((uint64_t)(NPAD - 1 - t) << 6) |
                               (uint64_t)__popcll(mk);
            }
        }
        __syncthreads();
        int C = s_cnt;
        if (C > SELCAP) C = SELCAP;

        // exact weighted rank (keys distinct) + scatter depths (pos >= NQ dropped)
        for (int i = tid; i < C; i += 512) {
            uint64_t k = s_sel[i];
            int wt = (int)(k & 63ull);
            int start = 0;
            for (int j = 0; j < C; ++j) {
                uint64_t kj = s_sel[j];               // broadcast read
                if (kj > k) start += (int)(kj & 63ull);
            }
            if (start < NQ) {
                int cn = (NPAD - 1) - (int)((k >> 6) & 8191ull);
                uint64_t mask = mb[cn];
                for (int u = 0; u < wt; ++u) {
                    int d = __builtin_ctzll(mask);
                    mask &= (mask - 1);
                    int pos = start + u;
                    if (pos < NQ) s_out[pos] = (cn << 6) | d;
                }
            }
        }
        __syncthreads();
    } else {
        // ======== ORDER REGIME ======== (boxes already in index order)
        int base = tid * 11;
        int cnts[11];
        int run = 0;
        #pragma unroll
        for (int u = 0; u < 11; ++u) {
            int t = base + u;
            int c = (t < NBOXES) ? __popcll(mb[t]) : 0;
            cnts[u] = c;
            run += c;
        }
        s_scan[tid] = run;
        __syncthreads();
        for (int off = 1; off < 512; off <<= 1) {
            int v = (tid >= off) ? s_scan[tid - off] : 0;
            __syncthreads();
            s_scan[tid] += v;
            __syncthreads();
        }
        int pos = s_scan[tid] - run;
        for (int u = 0; u < 11; ++u) {
            int t = base + u;
            if (t >= NBOXES) break;
            if (!cnts[u]) continue;
            if (pos >= NQ) break;
            uint64_t mask = mb[t];
            for (int i = 0; i < cnts[u]; ++i) {
                int d = __builtin_ctzll(mask);
                mask &= (mask - 1);
                if (pos < NQ) s_out[pos] = (t << 6) | d;
                ++pos;
            }
        }
        __syncthreads();
    }

    // ---- emit: direct lookup ----
    const float denom = 102.4f + 1e-6f;
    if (tid < NQ) {
        int v = s_out[tid];
        float X = 0.0f, Y = 0.0f, Z = 0.0f, pm = 1.0f;
        if (v >= 0) {
            int cn = v >> 6;
            int d  = v & 63;
            int c  = cn / NBOX;
            const float* bx = boxes + (b * NBOXES + cn) * 4;
            float x1 = bx[0], y1 = bx[1], x2 = bx[2], y2 = bx[3];
            float cx = (x1 + x2) * 0.5f, cy = (y1 + y2) * 0.5f;
            const float step = (60.0f - 1.0f) / 47.0f;
            float z = (d == ND - 1) ? 60.0f : 1.0f + (float)d * step;
            const float* Ki = s_Ki[c];
            float u0 = cx * z, u1 = cy * z;
            float pcx = Ki[0] * u0 + Ki[1] * u1 + Ki[2] * z;
            float pcy = Ki[3] * u0 + Ki[4] * u1 + Ki[5] * z;
            float pcz = Ki[6] * u0 + Ki[7] * u1 + Ki[8] * z;
            const float* Ep = E + (b * NCC + c) * 16;
            X = Ep[0] * pcx + Ep[1] * pcy + Ep[2]  * pcz + Ep[3];
            Y = Ep[4] * pcx + Ep[5] * pcy + Ep[6]  * pcz + Ep[7];
            Z = Ep[8] * pcx + Ep[9] * pcy + Ep[10] * pcz + Ep[11];
            pm = 0.0f;
        }
        float* o = out + (b * NQ + tid) * 3;
        o[0] = fminf(fmaxf((X + 51.2f) / denom, 0.0f), 1.0f);
        o[1] = fminf(fmaxf((Y + 51.2f) / denom, 0.0f), 1.0f);
        o[2] = fminf(fmaxf((Z + 51.2f) / denom, 0.0f), 1.0f);
        out[REFSZ + b * NQ + tid] = pm;
    }
}

extern "C" void kernel_launch(void* const* d_in, const int* in_sizes, int n_in,
                              void* d_out, int out_size, void* d_ws, size_t ws_size,
                              hipStream_t stream) {
    const float* boxes = (const float*)d_in[0];
    const float* K     = (const float*)d_in[1];
    const float* E     = (const float*)d_in[2];
    // ws: [0,345600) mask64 | [345600,518400) area_bits | [518400,551168) hist
    uint64_t* mask64    = (uint64_t*)d_ws;
    uint32_t* area_bits = (uint32_t*)((char*)d_ws + 345600);
    int*      histp     = (int*)((char*)d_ws + 518400);
    float*    out       = (float*)d_out;

    hipMemsetAsync(histp, 0, BB * NBIN * sizeof(int), stream);
    int nthreads = BB * NBOXES * TPB_BOX;   // 259200
    mask_kernel<<<(nthreads + 255) / 256, 256, 0, stream>>>(
        boxes, K, E, (uint8_t*)mask64, area_bits, histp);
    select_kernel<<<BB, 512, 0, stream>>>(mask64, area_bits, boxes, K, E, histp, out);
}

// Round 6
// 95.349 us; speedup vs baseline: 2.8746x; 2.8746x over previous
//
#include <hip/hip_runtime.h>
#include <math.h>
#include <stdint.h>

#define BB 8
#define NCC 6
#define NBOX 900
#define NBOXES (NCC * NBOX)      // 5400 boxes per batch
#define NBC (BB * NCC)           // 48 cameras
#define ND 48
#define TPB_BOX 6                // threads per box in mask kernel (8 depths each)
#define NQ 400
#define REFSZ (BB * NQ * 3)
#define NPAD 5408
#define NBIN 1024
#define SELCAP 640               // survivor capacity (<400 + boundary-bin pop)

// nan_to_num applied to an f32-rounded double (matches ref's _nan_to_num on the f32 inverse)
__device__ __forceinline__ float nnf(double x) {
    float v = (float)x;
    if (isnan(v)) return 0.0f;
    if (isinf(v)) return v > 0.0f ? 1e6f : -1e6f;
    return v;
}

__device__ void invert3x3(const float* __restrict__ Kp, float* __restrict__ Ki) {
    double a00 = Kp[0], a01 = Kp[1], a02 = Kp[2];
    double a10 = Kp[4], a11 = Kp[5], a12 = Kp[6];
    double a20 = Kp[8], a21 = Kp[9], a22 = Kp[10];
    double c00 = a11 * a22 - a12 * a21;
    double c10 = a12 * a20 - a10 * a22;
    double c20 = a10 * a21 - a11 * a20;
    double det = a00 * c00 + a01 * c10 + a02 * c20;
    double id  = 1.0 / det;
    Ki[0] = nnf(c00 * id); Ki[1] = nnf((a02 * a21 - a01 * a22) * id); Ki[2] = nnf((a01 * a12 - a02 * a11) * id);
    Ki[3] = nnf(c10 * id); Ki[4] = nnf((a00 * a22 - a02 * a20) * id); Ki[5] = nnf((a02 * a10 - a00 * a12) * id);
    Ki[6] = nnf(c20 * id); Ki[7] = nnf((a01 * a20 - a00 * a21) * id); Ki[8] = nnf((a00 * a11 - a01 * a10) * id);
}

__device__ void invert4x4(const float* __restrict__ Ep, float* __restrict__ Ei) {
    double m[4][8];
    for (int i = 0; i < 4; ++i)
        for (int j = 0; j < 4; ++j) {
            m[i][j]     = (double)Ep[i * 4 + j];
            m[i][4 + j] = (i == j) ? 1.0 : 0.0;
        }
    for (int col = 0; col < 4; ++col) {
        int piv = col; double best = fabs(m[col][col]);
        for (int r = col + 1; r < 4; ++r) {
            double v = fabs(m[r][col]);
            if (v > best) { best = v; piv = r; }
        }
        if (piv != col)
            for (int j = 0; j < 8; ++j) { double tmp = m[col][j]; m[col][j] = m[piv][j]; m[piv][j] = tmp; }
        double ipv = 1.0 / m[col][col];
        for (int j = 0; j < 8; ++j) m[col][j] *= ipv;
        for (int r = 0; r < 4; ++r) {
            if (r == col) continue;
            double f = m[r][col];
            if (f != 0.0)
                for (int j = 0; j < 8; ++j) m[r][j] -= f * m[col][j];
        }
    }
    for (int i = 0; i < 16; ++i) Ei[i] = nnf(m[i / 4][4 + (i & 3)]);
}

// ---------------- kernel 1: per-(box, j) mask over 8 depths ----------------
// Round-4 version: NO global histogram (device-scope atomic hot-spotting on
// ~50 live area bins cost 170 us in round 5 — G12).
__global__ __launch_bounds__(256) void mask_kernel(const float* __restrict__ boxes,
                                                   const float* __restrict__ K,
                                                   const float* __restrict__ E,
                                                   uint8_t* __restrict__ mask_bytes,
                                                   uint32_t* __restrict__ area_bits) {
    __shared__ float sKi[2][9];
    __shared__ float sEv[2][16];

    int gbase = blockIdx.x * 256;
    int bc_lo = gbase / (NBOX * TPB_BOX);
    int bc_hi = (gbase + 255) / (NBOX * TPB_BOX);
    if (bc_hi > NBC - 1) bc_hi = NBC - 1;
    if (threadIdx.x == 0) {
        invert3x3(K + bc_lo * 16, sKi[0]);
        invert4x4(E + bc_lo * 16, sEv[0]);
    }
    if (threadIdx.x == 1 && bc_hi != bc_lo) {
        invert3x3(K + bc_hi * 16, sKi[1]);
        invert4x4(E + bc_hi * 16, sEv[1]);
    }
    __syncthreads();

    int gtid = gbase + threadIdx.x;
    if (gtid >= BB * NBOXES * TPB_BOX) return;
    int box = gtid / TPB_BOX;
    int j   = gtid - box * TPB_BOX;
    int bc  = box / NBOX;

    const float* bx = boxes + box * 4;
    float x1 = bx[0], y1 = bx[1], x2 = bx[2], y2 = bx[3];
    float area  = (x2 - x1) * (y2 - y1);
    bool  valid = (area > 5.0f) && (area < 197120.0f);
    if (j == 0) {
        area_bits[box] = __float_as_uint(area);
        *(uint16_t*)(mask_bytes + box * 8 + 6) = 0;
    }

    uint32_t m8 = 0;
    if (valid) {
        int sel = (bc == bc_lo) ? 0 : 1;
        float Ki[9], Ev[16], Ep[12], Kp[11];
        #pragma unroll
        for (int i = 0; i < 9; ++i)  Ki[i] = sKi[sel][i];
        #pragma unroll
        for (int i = 0; i < 16; ++i) Ev[i] = sEv[sel][i];
        const float* Epp = E + bc * 16;
        #pragma unroll
        for (int i = 0; i < 12; ++i) Ep[i] = Epp[i];
        const float* Kpp = K + bc * 16;
        #pragma unroll
        for (int i = 0; i < 11; ++i) Kp[i] = Kpp[i];

        float cx = (x1 + x2) * 0.5f, cy = (y1 + y2) * 0.5f;
        const float step = (60.0f - 1.0f) / 47.0f;

        #pragma unroll
        for (int dd = 0; dd < 8; ++dd) {
            int d = j * 8 + dd;
            float z = (d == ND - 1) ? 60.0f : 1.0f + (float)d * step;
            float u0 = cx * z, u1 = cy * z;
            float pcx = Ki[0] * u0 + Ki[1] * u1 + Ki[2] * z;
            float pcy = Ki[3] * u0 + Ki[4] * u1 + Ki[5] * z;
            float pcz = Ki[6] * u0 + Ki[7] * u1 + Ki[8] * z;

            float X = Ep[0] * pcx + Ep[1] * pcy + Ep[2]  * pcz + Ep[3];
            float Y = Ep[4] * pcx + Ep[5] * pcy + Ep[6]  * pcz + Ep[7];
            float Z = Ep[8] * pcx + Ep[9] * pcy + Ep[10] * pcz + Ep[11];

            float q0 = Ev[0]  * X + Ev[1]  * Y + Ev[2]  * Z + Ev[3];
            float q1 = Ev[4]  * X + Ev[5]  * Y + Ev[6]  * Z + Ev[7];
            float q2 = Ev[8]  * X + Ev[9]  * Y + Ev[10] * Z + Ev[11];
            float q3 = Ev[12] * X + Ev[13] * Y + Ev[14] * Z + Ev[15];
            float w  = q3 + 1e-6f;
            float r0 = q0 / w, r1 = q1 / w, r2 = q2 / w;

            float p0 = Kp[0] * r0 + Kp[1] * r1 + Kp[2]  * r2;
            float p1 = Kp[4] * r0 + Kp[5] * r1 + Kp[6]  * r2;
            float p2 = Kp[8] * r0 + Kp[9] * r1 + Kp[10] * r2;
            float iz = p2 + 1e-6f;
            float ix = p0 / iz, iy = p1 / iz;

            float bs = 40.0f * (10.0f / (r2 + 1e-6f));
            bs = fminf(fmaxf(bs, 8.0f), 200.0f);
            float hh = bs / 2.0f;
            float px1 = ix - hh, py1 = iy - hh, px2 = ix + hh, py2 = iy + hh;

            float ix1 = fmaxf(px1, x1), iy1 = fmaxf(py1, y1);
            float ix2 = fminf(px2, x2), iy2 = fminf(py2, y2);
            float inter = fmaxf(ix2 - ix1, 0.0f) * fmaxf(iy2 - iy1, 0.0f);
            float a1 = (px2 - px1) * (py2 - py1);
            float iou = inter / (a1 + area - inter + 1e-6f);

            if (iou > 0.05f) m8 |= (1u << dd);
        }
    }
    mask_bytes[box * 8 + j] = (uint8_t)m8;
}

// ---------------- kernel 2: per-batch top-400 select + output ----------------
// Builds the 1024-bin weighted area histogram in LDS (block-local atomics),
// suffix-scans it to find boundary bin B* (all top-400 keys have bin >= B*),
// one-sweep compacts survivors, exact weighted rank, scatter, emit.
// Order regime (total <= 400): blocked prefix of per-box counts, scatter, emit.
__global__ __launch_bounds__(512) void select_kernel(const uint64_t* __restrict__ mask64,
                                                     const uint32_t* __restrict__ area_bits,
                                                     const float* __restrict__ boxes,
                                                     const float* __restrict__ K,
                                                     const float* __restrict__ E,
                                                     float* __restrict__ out) {
    int b   = blockIdx.x;
    int tid = threadIdx.x;
    int lane = tid & 63, wv = tid >> 6;
    const uint64_t* mb = mask64 + b * NBOXES;
    const uint32_t* ab = area_bits + b * NBOXES;

    __shared__ int      s_hist[NBIN];     // 4 KB
    __shared__ uint64_t s_sel[SELCAP];    // 5 KB
    __shared__ int      s_out[NQ];        // 1.6 KB  packed (cn<<6)|d, -1 = pad
    __shared__ int      s_scan[512];
    __shared__ int      s_wsum[8];
    __shared__ float    s_Ki[NCC][9];
    __shared__ int      s_B, s_cnt;

    if (tid < NCC) invert3x3(K + (b * NCC + tid) * 16, s_Ki[tid]);
    if (tid < NQ) s_out[tid] = -1;
    if (tid == 0) { s_B = 0; s_cnt = 0; }
    s_hist[tid] = 0;
    s_hist[tid + 512] = 0;
    __syncthreads();

    // ---- pass 1: LDS weighted histogram over boxes ----
    for (int t = tid; t < NBOXES; t += 512) {
        uint64_t mk = mb[t];
        if (!mk) continue;
        int bin = (int)(ab[t] >> 21) & (NBIN - 1);   // monotone in area (positive f32)
        atomicAdd(&s_hist[bin], __popcll(mk));
    }
    __syncthreads();

    // ---- suffix scan of the 1024-bin weighted histogram (2 bins/thread) ----
    int h0 = s_hist[2 * tid];
    int h1 = s_hist[2 * tid + 1];
    int w  = h0 + h1;
    int suf = w;
    #pragma unroll
    for (int off = 1; off < 64; off <<= 1) {
        int v = __shfl_down(suf, off);
        if (lane + off < 64) suf += v;
    }
    if (lane == 0) s_wsum[wv] = suf;      // wave total
    __syncthreads();
    int above_waves = 0, total = 0;
    #pragma unroll
    for (int ww = 0; ww < 8; ++ww) {
        int v = s_wsum[ww];
        total += v;
        if (ww > wv) above_waves += v;
    }
    int S_incl = suf + above_waves;        // weight of bins >= 2*tid
    int above  = S_incl - w;               // weight of bins >  2*tid+1
    if (total > NQ) {
        int s1 = above + h1;               // suffix(2t+1)
        if (s1 >= NQ && above < NQ)       s_B = 2 * tid + 1;
        else if (S_incl >= NQ && s1 < NQ) s_B = 2 * tid;
    }
    __syncthreads();

    if (total > NQ) {
        // ======== AREA REGIME ========
        int Bstar = s_B;
        for (int t = tid; t < NBOXES; t += 512) {
            uint64_t mk = mb[t];
            if (!mk) continue;
            uint32_t abv = ab[t];
            int bin = (int)(abv >> 21) & (NBIN - 1);
            if (bin >= Bstar) {
                int p = atomicAdd(&s_cnt, 1);
                if (p < SELCAP)
                    s_sel[p] = ((uint64_t)abv << 32) |
                               ((uint64_t)(NPAD - 1 - t) << 6) |
                               (uint64_t)__popcll(mk);
            }
        }
        __syncthreads();
        int C = s_cnt;
        if (C > SELCAP) C = SELCAP;

        // exact weighted rank (keys distinct) + scatter depths (pos >= NQ dropped)
        for (int i = tid; i < C; i += 512) {
            uint64_t k = s_sel[i];
            int wt = (int)(k & 63ull);
            int start = 0;
            for (int j = 0; j < C; ++j) {
                uint64_t kj = s_sel[j];               // broadcast read
                if (kj > k) start += (int)(kj & 63ull);
            }
            if (start < NQ) {
                int cn = (NPAD - 1) - (int)((k >> 6) & 8191ull);
                uint64_t mask = mb[cn];
                for (int u = 0; u < wt; ++u) {
                    int d = __builtin_ctzll(mask);
                    mask &= (mask - 1);
                    int pos = start + u;
                    if (pos < NQ) s_out[pos] = (cn << 6) | d;
                }
            }
        }
        __syncthreads();
    } else {
        // ======== ORDER REGIME ======== (boxes already in index order)
        int base = tid * 11;
        int cnts[11];
        int run = 0;
        #pragma unroll
        for (int u = 0; u < 11; ++u) {
            int t = base + u;
            int c = (t < NBOXES) ? __popcll(mb[t]) : 0;
            cnts[u] = c;
            run += c;
        }
        s_scan[tid] = run;
        __syncthreads();
        for (int off = 1; off < 512; off <<= 1) {
            int v = (tid >= off) ? s_scan[tid - off] : 0;
            __syncthreads();
            s_scan[tid] += v;
            __syncthreads();
        }
        int pos = s_scan[tid] - run;
        for (int u = 0; u < 11; ++u) {
            int t = base + u;
            if (t >= NBOXES) break;
            if (!cnts[u]) continue;
            if (pos >= NQ) break;
            uint64_t mask = mb[t];
            for (int i = 0; i < cnts[u]; ++i) {
                int d = __builtin_ctzll(mask);
                mask &= (mask - 1);
                if (pos < NQ) s_out[pos] = (t << 6) | d;
                ++pos;
            }
        }
        __syncthreads();
    }

    // ---- emit: direct lookup ----
    const float denom = 102.4f + 1e-6f;
    if (tid < NQ) {
        int v = s_out[tid];
        float X = 0.0f, Y = 0.0f, Z = 0.0f, pm = 1.0f;
        if (v >= 0) {
            int cn = v >> 6;
            int d  = v & 63;
            int c  = cn / NBOX;
            const float* bx = boxes + (b * NBOXES + cn) * 4;
            float x1 = bx[0], y1 = bx[1], x2 = bx[2], y2 = bx[3];
            float cx = (x1 + x2) * 0.5f, cy = (y1 + y2) * 0.5f;
            const float step = (60.0f - 1.0f) / 47.0f;
            float z = (d == ND - 1) ? 60.0f : 1.0f + (float)d * step;
            const float* Ki = s_Ki[c];
            float u0 = cx * z, u1 = cy * z;
            float pcx = Ki[0] * u0 + Ki[1] * u1 + Ki[2] * z;
            float pcy = Ki[3] * u0 + Ki[4] * u1 + Ki[5] * z;
            float pcz = Ki[6] * u0 + Ki[7] * u1 + Ki[8] * z;
            const float* Ep = E + (b * NCC + c) * 16;
            X = Ep[0] * pcx + Ep[1] * pcy + Ep[2]  * pcz + Ep[3];
            Y = Ep[4] * pcx + Ep[5] * pcy + Ep[6]  * pcz + Ep[7];
            Z = Ep[8] * pcx + Ep[9] * pcy + Ep[10] * pcz + Ep[11];
            pm = 0.0f;
        }
        float* o = out + (b * NQ + tid) * 3;
        o[0] = fminf(fmaxf((X + 51.2f) / denom, 0.0f), 1.0f);
        o[1] = fminf(fmaxf((Y + 51.2f) / denom, 0.0f), 1.0f);
        o[2] = fminf(fmaxf((Z + 51.2f) / denom, 0.0f), 1.0f);
        out[REFSZ + b * NQ + tid] = pm;
    }
}

extern "C" void kernel_launch(void* const* d_in, const int* in_sizes, int n_in,
                              void* d_out, int out_size, void* d_ws, size_t ws_size,
                              hipStream_t stream) {
    const float* boxes = (const float*)d_in[0];
    const float* K     = (const float*)d_in[1];
    const float* E     = (const float*)d_in[2];
    // ws: [0,345600) mask64 | [345600,518400) area_bits
    uint64_t* mask64    = (uint64_t*)d_ws;
    uint32_t* area_bits = (uint32_t*)((char*)d_ws + 345600);
    float*    out       = (float*)d_out;

    int nthreads = BB * NBOXES * TPB_BOX;   // 259200
    mask_kernel<<<(nthreads + 255) / 256, 256, 0, stream>>>(
        boxes, K, E, (uint8_t*)mask64, area_bits);
    select_kernel<<<BB, 512, 0, stream>>>(mask64, area_bits, boxes, K, E, out);
}